// Round 13
// baseline (630.099 us; speedup 1.0000x reference)
//
#include <hip/hip_runtime.h>

typedef unsigned short u16;
typedef __attribute__((ext_vector_type(8))) short bf16x8;   // 8 bf16 = 4 VGPRs
typedef __attribute__((ext_vector_type(4))) float f32x4;

__device__ __forceinline__ float bf2f(u16 u) {
    return __uint_as_float(((unsigned int)u) << 16);
}
__device__ __forceinline__ u16 f2bf(float f) {
    unsigned int u = __float_as_uint(f);
    u += 0x7fffu + ((u >> 16) & 1u);
    return (u16)(u >> 16);
}
__device__ __forceinline__ bf16x8 pack8(float4 a, float4 b) {
    bf16x8 r;
    r[0] = (short)f2bf(a.x); r[1] = (short)f2bf(a.y);
    r[2] = (short)f2bf(a.z); r[3] = (short)f2bf(a.w);
    r[4] = (short)f2bf(b.x); r[5] = (short)f2bf(b.y);
    r[6] = (short)f2bf(b.z); r[7] = (short)f2bf(b.w);
    return r;
}
// fma 8 bf16 lanes (packed in int4) into acc[8]
__device__ __forceinline__ void fma8(float* acc, float a, int4 v) {
    unsigned vx = (unsigned)v.x, vy = (unsigned)v.y, vz = (unsigned)v.z, vw = (unsigned)v.w;
    acc[0] = fmaf(a, bf2f((u16)(vx & 0xffff)), acc[0]);
    acc[1] = fmaf(a, bf2f((u16)(vx >> 16)), acc[1]);
    acc[2] = fmaf(a, bf2f((u16)(vy & 0xffff)), acc[2]);
    acc[3] = fmaf(a, bf2f((u16)(vy >> 16)), acc[3]);
    acc[4] = fmaf(a, bf2f((u16)(vz & 0xffff)), acc[4]);
    acc[5] = fmaf(a, bf2f((u16)(vz >> 16)), acc[5]);
    acc[6] = fmaf(a, bf2f((u16)(vw & 0xffff)), acc[6]);
    acc[7] = fmaf(a, bf2f((u16)(vw >> 16)), acc[7]);
}

// ---------------- CSR build (dst-indexed), reused by both GAT layers ----------
__global__ __launch_bounds__(256) void hist_kernel(const int* __restrict__ ei, int E, int N,
                                                   int* __restrict__ counts) {
    int i = blockIdx.x * 256 + threadIdx.x;
    if (i < E) atomicAdd(&counts[ei[E + i]], 1);
    else if (i < E + N) atomicAdd(&counts[i - E], 1);
}

// ---- 3-phase parallel exclusive scan over counts[N] -> offs[N+1], cursor[N] --
__global__ __launch_bounds__(256) void scan_p1(const int* __restrict__ counts, int N,
                                               int* __restrict__ excl, int* __restrict__ bsum) {
    __shared__ int tmp[256];
    int t = threadIdx.x, b = blockIdx.x, i = b * 256 + t;
    int v = (i < N) ? counts[i] : 0;
    tmp[t] = v;
    __syncthreads();
    for (int o = 1; o < 256; o <<= 1) {
        int u = (t >= o) ? tmp[t - o] : 0;
        __syncthreads();
        tmp[t] += u;
        __syncthreads();
    }
    if (i < N) excl[i] = tmp[t] - v;
    if (t == 255) bsum[b] = tmp[255];
}

__global__ __launch_bounds__(256) void scan_p2(const int* __restrict__ bsum, int nb,
                                               int* __restrict__ bbase, int* __restrict__ total) {
    __shared__ int tmp[256];
    int t = threadIdx.x;
    int run = 0;
    for (int base = 0; base < nb; base += 256) {
        int idx = base + t;
        int v = (idx < nb) ? bsum[idx] : 0;
        tmp[t] = v;
        __syncthreads();
        for (int o = 1; o < 256; o <<= 1) {
            int u = (t >= o) ? tmp[t - o] : 0;
            __syncthreads();
            tmp[t] += u;
            __syncthreads();
        }
        if (idx < nb) bbase[idx] = run + tmp[t] - v;
        run += tmp[255];
        __syncthreads();
    }
    if (t == 0) *total = run;
}

__global__ __launch_bounds__(256) void scan_p3(const int* __restrict__ excl, const int* __restrict__ bbase,
                                               const int* __restrict__ total, int N,
                                               int* __restrict__ offs, int* __restrict__ cursor) {
    int t = threadIdx.x, b = blockIdx.x, i = b * 256 + t;
    if (i < N) {
        int o = excl[i] + bbase[b];
        offs[i] = o;
        cursor[i] = o;
    }
    if (i == 0) offs[N] = *total;
}

__global__ __launch_bounds__(256) void scatter_kernel(const int* __restrict__ ei, int E, int N,
                                                      int* __restrict__ cursor, int* __restrict__ csr) {
    int i = blockIdx.x * 256 + threadIdx.x;
    if (i < E) {
        int d = ei[E + i];
        int p = atomicAdd(&cursor[d], 1);
        csr[p] = ei[i];
    } else if (i < E + N) {
        int n = i - E;
        int p = atomicAdd(&cursor[n], 1);
        csr[p] = n;
    }
}

// ---------------- pack W [K,256] f32 into MFMA B-fragment order (bf16) --------
__global__ __launch_bounds__(256) void packW_kernel(const float* __restrict__ W, int KS,
                                                    u16* __restrict__ out) {
    int idx = blockIdx.x * 256 + threadIdx.x;
    int total = 16 * KS * 512;
    if (idx >= total) return;
    int j = idx & 7;
    int lane = (idx >> 3) & 63;
    int rest = idx >> 9;        // ct*KS + ks
    int ks = rest % KS;
    int ct = rest / KS;
    int k = ks * 32 + (lane >> 4) * 8 + j;
    int n = ct * 16 + (lane & 15);
    out[idx] = f2bf(W[k * 256 + n]);
}

// ---------------- MFMA GEMM (32 rows/wave) + fused epilogue --------------------
// MODE 0: A = raw f32 [N,K] (layer 1 input x; converts to bf16 in-register)
// MODE 1: A = bf16 agg [N,256] with fused bn1-apply + relu (y1 never hits HBM)
// Epilogue: LDS transpose -> coalesced bf16 store + per-row al_s/al_d dots.
template <int K, int H, int MODE>
__global__ __launch_bounds__(256) void gemm_mfma(const void* __restrict__ Ain,
                                                 const u16* __restrict__ Bp,
                                                 u16* __restrict__ O,
                                                 const float* __restrict__ as_,
                                                 const float* __restrict__ ad_,
                                                 float* __restrict__ als,
                                                 float* __restrict__ ald,
                                                 const float* __restrict__ bsum,
                                                 const float* __restrict__ bsq,
                                                 const float* __restrict__ g,
                                                 const float* __restrict__ be,
                                                 int Nrows) {
    constexpr int KS = K / 32;
    __shared__ u16 lds[4][32 * 256];   // 64 KB/block
    __shared__ float sc_s[256], sh_s[256];
    if (MODE == 1) {  // bn1 scale/shift table (all threads reach the barrier)
        int t = threadIdx.x;
        float inv = 1.f / (float)Nrows;
        float mm = bsum[t] * inv;
        float vv = fmaxf(bsq[t] * inv - mm * mm, 0.f);
        float sc = rsqrtf(vv + 1e-5f) * g[t];
        sc_s[t] = sc;
        sh_s[t] = be[t] - mm * sc;
        __syncthreads();
    }
    int wave = threadIdx.x >> 6, lane = threadIdx.x & 63;
    int tile = blockIdx.x * 4 + wave;
    int row0 = tile * 32;
    if (row0 >= Nrows) return;
    int m = lane & 15, q = lane >> 4;
    int r0c = min(row0 + m, Nrows - 1);
    int r1c = min(row0 + 16 + m, Nrows - 1);

    bf16x8 af0[KS], af1[KS];
    if (MODE == 0) {
        const float* A = (const float*)Ain;
        const float* a0 = A + (size_t)r0c * K + q * 8;
        const float* a1 = A + (size_t)r1c * K + q * 8;
#pragma unroll
        for (int ks = 0; ks < KS; ks++) {
            af0[ks] = pack8(*(const float4*)(a0 + ks * 32), *(const float4*)(a0 + ks * 32 + 4));
            af1[ks] = pack8(*(const float4*)(a1 + ks * 32), *(const float4*)(a1 + ks * 32 + 4));
        }
    } else {
        const u16* A = (const u16*)Ain;
        const u16* a0 = A + (size_t)r0c * K + q * 8;
        const u16* a1 = A + (size_t)r1c * K + q * 8;
#pragma unroll
        for (int ks = 0; ks < KS; ks++) {
            int cb = ks * 32 + q * 8;
            float4 sc0 = *(const float4*)&sc_s[cb];
            float4 sc1 = *(const float4*)&sc_s[cb + 4];
            float4 sh0 = *(const float4*)&sh_s[cb];
            float4 sh1 = *(const float4*)&sh_s[cb + 4];
            ushort4 u0 = *(const ushort4*)(a0 + ks * 32);
            ushort4 u1 = *(const ushort4*)(a0 + ks * 32 + 4);
            float4 v0 = make_float4(fmaxf(fmaf(bf2f(u0.x), sc0.x, sh0.x), 0.f),
                                    fmaxf(fmaf(bf2f(u0.y), sc0.y, sh0.y), 0.f),
                                    fmaxf(fmaf(bf2f(u0.z), sc0.z, sh0.z), 0.f),
                                    fmaxf(fmaf(bf2f(u0.w), sc0.w, sh0.w), 0.f));
            float4 v1 = make_float4(fmaxf(fmaf(bf2f(u1.x), sc1.x, sh1.x), 0.f),
                                    fmaxf(fmaf(bf2f(u1.y), sc1.y, sh1.y), 0.f),
                                    fmaxf(fmaf(bf2f(u1.z), sc1.z, sh1.z), 0.f),
                                    fmaxf(fmaf(bf2f(u1.w), sc1.w, sh1.w), 0.f));
            af0[ks] = pack8(v0, v1);
            ushort4 w0 = *(const ushort4*)(a1 + ks * 32);
            ushort4 w1 = *(const ushort4*)(a1 + ks * 32 + 4);
            float4 x0 = make_float4(fmaxf(fmaf(bf2f(w0.x), sc0.x, sh0.x), 0.f),
                                    fmaxf(fmaf(bf2f(w0.y), sc0.y, sh0.y), 0.f),
                                    fmaxf(fmaf(bf2f(w0.z), sc0.z, sh0.z), 0.f),
                                    fmaxf(fmaf(bf2f(w0.w), sc0.w, sh0.w), 0.f));
            float4 x1 = make_float4(fmaxf(fmaf(bf2f(w1.x), sc1.x, sh1.x), 0.f),
                                    fmaxf(fmaf(bf2f(w1.y), sc1.y, sh1.y), 0.f),
                                    fmaxf(fmaf(bf2f(w1.z), sc1.z, sh1.z), 0.f),
                                    fmaxf(fmaf(bf2f(w1.w), sc1.w, sh1.w), 0.f));
            af1[ks] = pack8(x0, x1);
        }
    }

    u16* myl = lds[wave];
#pragma unroll
    for (int ct2 = 0; ct2 < 8; ct2++) {
        int ct0 = ct2 * 2;
        f32x4 a00 = {0.f, 0.f, 0.f, 0.f}, a01 = {0.f, 0.f, 0.f, 0.f};
        f32x4 a10 = {0.f, 0.f, 0.f, 0.f}, a11 = {0.f, 0.f, 0.f, 0.f};
        const u16* bp0 = Bp + ((size_t)(ct0 * KS) * 64 + lane) * 8;
        const u16* bp1 = bp0 + (size_t)KS * 512;
#pragma unroll
        for (int ks = 0; ks < KS; ks++) {   // 4 independent chains per B pair
            bf16x8 b0 = *(const bf16x8*)(bp0 + (size_t)ks * 512);
            bf16x8 b1 = *(const bf16x8*)(bp1 + (size_t)ks * 512);
            a00 = __builtin_amdgcn_mfma_f32_16x16x32_bf16(af0[ks], b0, a00, 0, 0, 0);
            a01 = __builtin_amdgcn_mfma_f32_16x16x32_bf16(af0[ks], b1, a01, 0, 0, 0);
            a10 = __builtin_amdgcn_mfma_f32_16x16x32_bf16(af1[ks], b0, a10, 0, 0, 0);
            a11 = __builtin_amdgcn_mfma_f32_16x16x32_bf16(af1[ks], b1, a11, 0, 0, 0);
        }
        // C/D layout: col = lane&15, row = (lane>>4)*4 + r   [verified m89]
#pragma unroll
        for (int r = 0; r < 4; r++) {
            myl[(q * 4 + r) * 256 + ct0 * 16 + m] = f2bf(a00[r]);
            myl[(q * 4 + r) * 256 + ct0 * 16 + 16 + m] = f2bf(a01[r]);
            myl[(16 + q * 4 + r) * 256 + ct0 * 16 + m] = f2bf(a10[r]);
            myl[(16 + q * 4 + r) * 256 + ct0 * 16 + 16 + m] = f2bf(a11[r]);
        }
    }
    // epilogue: coalesced store + al dot (same-wave LDS, no barrier needed)
    int c8 = (lane & 31) * 8;
    float4 s0 = *(const float4*)(as_ + c8);
    float4 s1 = *(const float4*)(as_ + c8 + 4);
    float4 d0 = *(const float4*)(ad_ + c8);
    float4 d1 = *(const float4*)(ad_ + c8 + 4);
#pragma unroll
    for (int p = 0; p < 16; p++) {
        int row = p * 2 + (lane >> 5);
        if (row0 + row >= Nrows) continue;
        int4 v = *(const int4*)&myl[row * 256 + c8];
        *(int4*)&O[(size_t)(row0 + row) * 256 + c8] = v;
        float f0 = bf2f((u16)(v.x & 0xffff)), f1 = bf2f((u16)((unsigned)v.x >> 16));
        float f2 = bf2f((u16)(v.y & 0xffff)), f3 = bf2f((u16)((unsigned)v.y >> 16));
        float f4 = bf2f((u16)(v.z & 0xffff)), f5 = bf2f((u16)((unsigned)v.z >> 16));
        float f6 = bf2f((u16)(v.w & 0xffff)), f7 = bf2f((u16)((unsigned)v.w >> 16));
        float ps = f0 * s0.x + f1 * s0.y + f2 * s0.z + f3 * s0.w +
                   f4 * s1.x + f5 * s1.y + f6 * s1.z + f7 * s1.w;
        float pd = f0 * d0.x + f1 * d0.y + f2 * d0.z + f3 * d0.w +
                   f4 * d1.x + f5 * d1.y + f6 * d1.z + f7 * d1.w;
        const int W = (H == 4) ? 8 : 32;
#pragma unroll
        for (int o = 1; o < W; o <<= 1) {
            ps += __shfl_xor(ps, o);
            pd += __shfl_xor(pd, o);
        }
        if (H == 4) {
            if ((lane & 7) == 0) {
                int head = (lane & 31) >> 3;
                als[(row0 + row) * 4 + head] = ps;
                ald[(row0 + row) * 4 + head] = pd;
            }
        } else {
            if ((lane & 31) == 0) {
                als[row0 + row] = ps;
                ald[row0 + row] = pd;
            }
        }
    }
}

// ---------------- fused GAT softmax + accumulate + BN-stats -------------------
// Half-wave (32 lanes) per dst node; lane covers 8 cols via one int4 load.
// After the gather, per-column sum/sumsq accumulate into per-block LDS
// (atomics, <=8-way contention), flushed as 512 global atomics per block.
// Eliminates the separate bn_stats pass (25 MB re-read per layer).
template <int H>
__global__ __launch_bounds__(256) void gat_fused_kernel(const int* __restrict__ offs,
                                                        const int* __restrict__ csr,
                                                        const float* __restrict__ als,
                                                        const float* __restrict__ ald,
                                                        const u16* __restrict__ h,
                                                        u16* __restrict__ out,
                                                        float* __restrict__ gsum,
                                                        float* __restrict__ gsq, int N) {
    __shared__ float lalpha[8][32 * H];
    __shared__ int lsrc[8][32];
    __shared__ float ssum[256], ssq[256];
    int t = threadIdx.x;
    ssum[t] = 0.f;
    ssq[t] = 0.f;
    __syncthreads();
    int hw = t >> 5;          // half-wave in block (0..7)
    int lane = t & 31;        // lane within half-wave
    int w = (blockIdx.x * 256 + t) >> 5;
    if (w < N) {
        int s0 = offs[w], s1 = offs[w + 1];
        float adl[H], e0[H], m[H], den[H];
#pragma unroll
        for (int hh = 0; hh < H; hh++) { adl[hh] = ald[w * H + hh]; m[hh] = -1e30f; }
        int i0 = s0 + lane;
        bool have = (i0 < s1);
        int src0 = 0;
        if (have) {
            src0 = csr[i0];
            if (H == 4) {
                float4 av = ((const float4*)als)[src0];
                float tmp[4] = {av.x, av.y, av.z, av.w};
#pragma unroll
                for (int hh = 0; hh < 4; hh++) {
                    float e = tmp[hh] + adl[hh];
                    e = e > 0.f ? e : 0.2f * e;
                    e0[hh] = e; m[hh] = e;
                }
            } else {
                float e = als[src0] + adl[0];
                e = e > 0.f ? e : 0.2f * e;
                e0[0] = e; m[0] = e;
            }
        }
        for (int i = i0 + 32; i < s1; i += 32) {  // rare: deg > 32
            int s = csr[i];
#pragma unroll
            for (int hh = 0; hh < H; hh++) {
                float e = als[s * H + hh] + adl[hh];
                e = e > 0.f ? e : 0.2f * e;
                m[hh] = fmaxf(m[hh], e);
            }
        }
#pragma unroll
        for (int hh = 0; hh < H; hh++)
            for (int o = 16; o; o >>= 1) m[hh] = fmaxf(m[hh], __shfl_xor(m[hh], o));
#pragma unroll
        for (int hh = 0; hh < H; hh++) den[hh] = have ? __expf(e0[hh] - m[hh]) : 0.f;
        for (int i = i0 + 32; i < s1; i += 32) {
            int s = csr[i];
#pragma unroll
            for (int hh = 0; hh < H; hh++) {
                float e = als[s * H + hh] + adl[hh];
                e = e > 0.f ? e : 0.2f * e;
                den[hh] += __expf(e - m[hh]);
            }
        }
#pragma unroll
        for (int hh = 0; hh < H; hh++)
            for (int o = 16; o; o >>= 1) den[hh] += __shfl_xor(den[hh], o);
        float rden[H];
#pragma unroll
        for (int hh = 0; hh < H; hh++) rden[hh] = 1.f / (den[hh] + 1e-16f);
        // park chunk-0 alpha/src in per-half-wave LDS (same-wave DS order)
        if (have) {
            lsrc[hw][lane] = src0;
#pragma unroll
            for (int hh = 0; hh < H; hh++)
                lalpha[hw][lane * H + hh] = __expf(e0[hh] - m[hh]) * rden[hh];
        }
        int deg = s1 - s0;
        int cend = min(deg, 32);
        int myh = (H == 4) ? (lane >> 3) : 0;   // head = (lane*8)/64
        const int4* h16 = (const int4*)h;       // 32 int4 per 256-col row
        const float* la = lalpha[hw];
        const int* ls = lsrc[hw];
        float acc[8];
#pragma unroll
        for (int k2 = 0; k2 < 8; k2++) acc[k2] = 0.f;
        int i = 0;
        for (; i + 4 <= cend; i += 4) {
            int sa = ls[i], sb = ls[i + 1], sc = ls[i + 2], sd = ls[i + 3];
            float aa = la[i * H + myh];
            float ab = la[(i + 1) * H + myh];
            float ac = la[(i + 2) * H + myh];
            float ad = la[(i + 3) * H + myh];
            int4 ha = h16[(size_t)sa * 32 + lane];
            int4 hb = h16[(size_t)sb * 32 + lane];
            int4 hc = h16[(size_t)sc * 32 + lane];
            int4 hd = h16[(size_t)sd * 32 + lane];
            fma8(acc, aa, ha);
            fma8(acc, ab, hb);
            fma8(acc, ac, hc);
            fma8(acc, ad, hd);
        }
        for (; i < cend; i++) {
            int s = ls[i];
            float a = la[i * H + myh];
            fma8(acc, a, h16[(size_t)s * 32 + lane]);
        }
        for (int j = s0 + 32; j < s1; j++) {  // rare deg>32 tail: recompute alpha
            int s = csr[j];
            float e = als[s * H + myh] + adl[myh];
            e = e > 0.f ? e : 0.2f * e;
            float a = __expf(e - m[myh]) * rden[myh];
            fma8(acc, a, h16[(size_t)s * 32 + lane]);
        }
        int4 o;
        o.x = (int)((unsigned)f2bf(acc[0]) | ((unsigned)f2bf(acc[1]) << 16));
        o.y = (int)((unsigned)f2bf(acc[2]) | ((unsigned)f2bf(acc[3]) << 16));
        o.z = (int)((unsigned)f2bf(acc[4]) | ((unsigned)f2bf(acc[5]) << 16));
        o.w = (int)((unsigned)f2bf(acc[6]) | ((unsigned)f2bf(acc[7]) << 16));
        ((int4*)out)[(size_t)w * 32 + lane] = o;
        // per-block column stats (cols lane*8 .. lane*8+7)
#pragma unroll
        for (int k2 = 0; k2 < 8; k2++) {
            int col = lane * 8 + k2;
            atomicAdd(&ssum[col], acc[k2]);
            atomicAdd(&ssq[col], acc[k2] * acc[k2]);
        }
    }
    __syncthreads();
    float sv = ssum[t], qv = ssq[t];
    if (sv != 0.f || qv != 0.f) {
        atomicAdd(&gsum[t], sv);
        atomicAdd(&gsq[t], qv);
    }
}

// layer 2: bn-apply + relu + fused global-mean-pool (batch sorted)
__global__ __launch_bounds__(256) void bn_apply_pool(const u16* __restrict__ agg,
                                                     const float* __restrict__ sum,
                                                     const float* __restrict__ sq,
                                                     const float* __restrict__ g,
                                                     const float* __restrict__ be,
                                                     const int* __restrict__ batch,
                                                     u16* __restrict__ out,
                                                     float* __restrict__ pools,
                                                     int* __restrict__ cnt, int N) {
    int t = threadIdx.x;
    float inv = 1.f / (float)N;
    float mm = sum[t] * inv;
    float vv = fmaxf(sq[t] * inv - mm * mm, 0.f);
    float sc = rsqrtf(vv + 1e-5f) * g[t];
    float sh = be[t] - mm * sc;
    int rows = (N + gridDim.x - 1) / gridDim.x;
    int r0 = blockIdx.x * rows, r1 = min(r0 + rows, N);
    if (r0 >= r1) return;
    float acc = 0.f;
    int cur = batch[r0], c0 = 0;
    for (int r = r0; r < r1; r++) {
        int b = batch[r];  // wave-uniform scalar load
        if (b != cur) {
            atomicAdd(&pools[cur * 256 + t], acc);
            if (t == 0) atomicAdd(&cnt[cur], c0);
            acc = 0.f; c0 = 0; cur = b;
        }
        float v = bf2f(agg[(size_t)r * 256 + t]);
        float y = fmaxf(fmaf(v, sc, sh), 0.f);
        out[(size_t)r * 256 + t] = f2bf(y);
        acc += y; c0++;
    }
    atomicAdd(&pools[cur * 256 + t], acc);
    if (t == 0) atomicAdd(&cnt[cur], c0);
}

// shared = relu(gf @ W_sh + b_sh) fused with heads; one block per graph
__global__ __launch_bounds__(256) void shared_head_kernel(const float* __restrict__ pools,
                                                          const int* __restrict__ cnt,
                                                          const float* __restrict__ Wsh,
                                                          const float* __restrict__ bsh,
                                                          const float* __restrict__ Wnode,
                                                          const float* __restrict__ Wcrit,
                                                          const float* __restrict__ bcrit,
                                                          const float* __restrict__ Wtype,
                                                          const float* __restrict__ btype,
                                                          const u16* __restrict__ xn,
                                                          const int* __restrict__ tgt,
                                                          float* __restrict__ gdot,
                                                          float* __restrict__ out_tail) {
    __shared__ float gf[256], red[256];
    int b = blockIdx.x, t = threadIdx.x;
    gf[t] = pools[b * 256 + t] / fmaxf((float)cnt[b], 1.f);
    __syncthreads();
    float acc = bsh[t];
    for (int k = 0; k < 256; k++) acc = fmaf(gf[k], Wsh[k * 256 + t], acc);
    float s = fmaxf(acc, 0.f);
    int tn = tgt[b];
    float xnt = bf2f(xn[(size_t)tn * 256 + t]);
    float pg = s * Wnode[256 + t];
    float pv = s * Wcrit[t];
    float pt0 = s * Wtype[t * 4 + 0] + xnt * Wtype[(256 + t) * 4 + 0];
    float pt1 = s * Wtype[t * 4 + 1] + xnt * Wtype[(256 + t) * 4 + 1];
    float pt2 = s * Wtype[t * 4 + 2] + xnt * Wtype[(256 + t) * 4 + 2];
    float pt3 = s * Wtype[t * 4 + 3] + xnt * Wtype[(256 + t) * 4 + 3];
    auto bred = [&](float v) -> float {
        __syncthreads();
        red[t] = v;
        __syncthreads();
        for (int o = 128; o; o >>= 1) {
            if (t < o) red[t] += red[t + o];
            __syncthreads();
        }
        return red[0];
    };
    float rg = bred(pg);
    float rv = bred(pv);
    float r0 = bred(pt0);
    float r1 = bred(pt1);
    float r2 = bred(pt2);
    float r3 = bred(pt3);
    if (t == 0) {
        gdot[b] = rg;
        out_tail[32 + b] = rv + bcrit[0];
        out_tail[b * 4 + 0] = r0 + btype[0];
        out_tail[b * 4 + 1] = r1 + btype[1];
        out_tail[b * 4 + 2] = r2 + btype[2];
        out_tail[b * 4 + 3] = r3 + btype[3];
    }
}

// node_scores: one wave per node (bf16 x_nodes)
__global__ __launch_bounds__(256) void node_scores_kernel(const u16* __restrict__ xn,
                                                          const float* __restrict__ Wnode, const float* __restrict__ bnode,
                                                          const int* __restrict__ batch, const float* __restrict__ gdot,
                                                          float* __restrict__ out, int N) {
    int w = (blockIdx.x * 256 + threadIdx.x) >> 6;
    int lane = threadIdx.x & 63;
    if (w >= N) return;
    ushort4 xv = ((const ushort4*)(xn + (size_t)w * 256))[lane];
    float4 wv = ((const float4*)Wnode)[lane];
    float p = bf2f(xv.x) * wv.x + bf2f(xv.y) * wv.y + bf2f(xv.z) * wv.z + bf2f(xv.w) * wv.w;
    for (int o = 32; o; o >>= 1) p += __shfl_xor(p, o);
    if (lane == 0) out[w] = p + gdot[batch[w]] + bnode[0];
}

extern "C" void kernel_launch(void* const* d_in, const int* in_sizes, int n_in,
                              void* d_out, int out_size, void* d_ws, size_t ws_size,
                              hipStream_t stream) {
    const float* x = (const float*)d_in[0];
    const int* ei = (const int*)d_in[1];
    const int* batch = (const int*)d_in[2];
    const int* tgt = (const int*)d_in[3];
    const float* W1 = (const float*)d_in[4];
    const float* a1s = (const float*)d_in[5];
    const float* a1d = (const float*)d_in[6];
    // b1 (d_in[7]) / b2 (d_in[11]): constant column shifts cancel exactly in BatchNorm
    const float* W2 = (const float*)d_in[8];
    const float* a2s = (const float*)d_in[9];
    const float* a2d = (const float*)d_in[10];
    const float* g1 = (const float*)d_in[12];
    const float* be1 = (const float*)d_in[13];
    const float* g2 = (const float*)d_in[14];
    const float* be2 = (const float*)d_in[15];
    const float* Wsh = (const float*)d_in[16];
    const float* bsh = (const float*)d_in[17];
    const float* Wnode = (const float*)d_in[18];
    const float* bnode = (const float*)d_in[19];
    const float* Wtype = (const float*)d_in[20];
    const float* btype = (const float*)d_in[21];
    const float* Wcrit = (const float*)d_in[22];
    const float* bcrit = (const float*)d_in[23];

    const int N = in_sizes[2];
    const int E = in_sizes[1] / 2;
    const int Et = E + N;
    const int nb = (N + 255) / 256;   // scan blocks

    // ---- workspace carve (~85 MB) ----
    char* w = (char*)d_ws;
    size_t off = 0;
    auto carve = [&](size_t bytes) -> char* {
        char* p = w + off;
        off = (off + bytes + 255) & ~(size_t)255;
        return p;
    };
    u16* agg_bf = (u16*)carve((size_t)N * 256 * 2);    // bf16 aggregation (both layers)
    u16* h_bf = (u16*)carve((size_t)N * 256 * 2);      // h1 -> h2 (gemm outputs)
    u16* y_bf = (u16*)carve((size_t)N * 256 * 2);      // x_nodes (bn2 out)
    u16* W1p = (u16*)carve(16 * 2 * 512 * 2);          // packed W1 frags
    u16* W2p = (u16*)carve(16 * 8 * 512 * 2);          // packed W2 frags
    float* al1s = (float*)carve((size_t)N * 4 * 4);
    float* al1d = (float*)carve((size_t)N * 4 * 4);
    float* al2s = (float*)carve((size_t)N * 4);
    float* al2d = (float*)carve((size_t)N * 4);
    int* offs = (int*)carve((size_t)(N + 1) * 4);
    int* cursor = (int*)carve((size_t)N * 4);
    int* csr = (int*)carve((size_t)Et * 4);
    int* excl = (int*)carve((size_t)N * 4);
    int* bsum = (int*)carve((size_t)nb * 4);
    int* bbase = (int*)carve((size_t)nb * 4);
    int* stotal = (int*)carve(64);
    float* gdot = (float*)carve(64);
    char* zero0 = w + off;
    int* counts = (int*)carve((size_t)N * 4);
    float* bn1s = (float*)carve(1024);
    float* bn1q = (float*)carve(1024);
    float* bn2s = (float*)carve(1024);
    float* bn2q = (float*)carve(1024);
    float* pools = (float*)carve(8 * 256 * 4);
    int* cnt = (int*)carve(64);
    size_t zbytes = (size_t)((w + off) - zero0);
    hipMemsetAsync(zero0, 0, zbytes, stream);

    int wavesPerGrid = (N + 3) / 4;                  // 4 node-waves per 256-thread block
    int halfGrid = (N + 7) / 8;                      // 8 node-half-waves per block
    int mfmaGrid = (((N + 31) / 32) + 3) / 4;        // 4 32-row tiles (waves) per block

    // ---- CSR build (3-phase parallel scan) + weight prep ----
    hist_kernel<<<(Et + 255) / 256, 256, 0, stream>>>(ei, E, N, counts);
    scan_p1<<<nb, 256, 0, stream>>>(counts, N, excl, bsum);
    scan_p2<<<1, 256, 0, stream>>>(bsum, nb, bbase, stotal);
    scan_p3<<<nb, 256, 0, stream>>>(excl, bbase, stotal, N, offs, cursor);
    scatter_kernel<<<(Et + 255) / 256, 256, 0, stream>>>(ei, E, N, cursor, csr);
    packW_kernel<<<(16 * 2 * 512 + 255) / 256, 256, 0, stream>>>(W1, 2, W1p);
    packW_kernel<<<(16 * 8 * 512 + 255) / 256, 256, 0, stream>>>(W2, 8, W2p);

    // ---- layer 1: GAT(4 heads); x converted to bf16 in gemm A-load ----
    gemm_mfma<64, 4, 0><<<mfmaGrid, 256, 0, stream>>>(x, W1p, h_bf, a1s, a1d, al1s, al1d,
                                                      bn1s, bn1q, g1, be1, N);
    gat_fused_kernel<4><<<halfGrid, 256, 0, stream>>>(offs, csr, al1s, al1d, h_bf, agg_bf,
                                                      bn1s, bn1q, N);

    // ---- layer 2: bn1-apply fused into gemm A-load; GAT(1) + BN2 + pool ----
    gemm_mfma<256, 1, 1><<<mfmaGrid, 256, 0, stream>>>(agg_bf, W2p, h_bf, a2s, a2d, al2s, al2d,
                                                       bn1s, bn1q, g1, be1, N);
    gat_fused_kernel<1><<<halfGrid, 256, 0, stream>>>(offs, csr, al2s, al2d, h_bf, agg_bf,
                                                      bn2s, bn2q, N);
    bn_apply_pool<<<1024, 256, 0, stream>>>(agg_bf, bn2s, bn2q, g2, be2, batch, y_bf, pools, cnt, N);

    // ---- heads ----
    shared_head_kernel<<<8, 256, 0, stream>>>(pools, cnt, Wsh, bsh, Wnode, Wcrit, bcrit,
                                              Wtype, btype, y_bf, tgt, gdot, (float*)d_out + N);
    node_scores_kernel<<<wavesPerGrid, 256, 0, stream>>>(y_bf, Wnode, bnode, batch, gdot,
                                                         (float*)d_out, N);
}

// Round 14
// 569.459 us; speedup vs baseline: 1.1065x; 1.1065x over previous
//
#include <hip/hip_runtime.h>

typedef unsigned short u16;
typedef __attribute__((ext_vector_type(8))) short bf16x8;   // 8 bf16 = 4 VGPRs
typedef __attribute__((ext_vector_type(4))) float f32x4;

__device__ __forceinline__ float bf2f(u16 u) {
    return __uint_as_float(((unsigned int)u) << 16);
}
__device__ __forceinline__ u16 f2bf(float f) {
    unsigned int u = __float_as_uint(f);
    u += 0x7fffu + ((u >> 16) & 1u);
    return (u16)(u >> 16);
}
__device__ __forceinline__ bf16x8 pack8(float4 a, float4 b) {
    bf16x8 r;
    r[0] = (short)f2bf(a.x); r[1] = (short)f2bf(a.y);
    r[2] = (short)f2bf(a.z); r[3] = (short)f2bf(a.w);
    r[4] = (short)f2bf(b.x); r[5] = (short)f2bf(b.y);
    r[6] = (short)f2bf(b.z); r[7] = (short)f2bf(b.w);
    return r;
}
// fma 8 bf16 lanes (packed in int4) into acc[8]
__device__ __forceinline__ void fma8(float* acc, float a, int4 v) {
    unsigned vx = (unsigned)v.x, vy = (unsigned)v.y, vz = (unsigned)v.z, vw = (unsigned)v.w;
    acc[0] = fmaf(a, bf2f((u16)(vx & 0xffff)), acc[0]);
    acc[1] = fmaf(a, bf2f((u16)(vx >> 16)), acc[1]);
    acc[2] = fmaf(a, bf2f((u16)(vy & 0xffff)), acc[2]);
    acc[3] = fmaf(a, bf2f((u16)(vy >> 16)), acc[3]);
    acc[4] = fmaf(a, bf2f((u16)(vz & 0xffff)), acc[4]);
    acc[5] = fmaf(a, bf2f((u16)(vz >> 16)), acc[5]);
    acc[6] = fmaf(a, bf2f((u16)(vw & 0xffff)), acc[6]);
    acc[7] = fmaf(a, bf2f((u16)(vw >> 16)), acc[7]);
}

// ---------------- CSR build (dst-indexed), reused by both GAT layers ----------
__global__ __launch_bounds__(256) void hist_kernel(const int* __restrict__ ei, int E, int N,
                                                   int* __restrict__ counts) {
    int i = blockIdx.x * 256 + threadIdx.x;
    if (i < E) atomicAdd(&counts[ei[E + i]], 1);
    else if (i < E + N) atomicAdd(&counts[i - E], 1);
}

// ---- 3-phase parallel exclusive scan over counts[N] -> offs[N+1], cursor[N] --
__global__ __launch_bounds__(256) void scan_p1(const int* __restrict__ counts, int N,
                                               int* __restrict__ excl, int* __restrict__ bsum) {
    __shared__ int tmp[256];
    int t = threadIdx.x, b = blockIdx.x, i = b * 256 + t;
    int v = (i < N) ? counts[i] : 0;
    tmp[t] = v;
    __syncthreads();
    for (int o = 1; o < 256; o <<= 1) {
        int u = (t >= o) ? tmp[t - o] : 0;
        __syncthreads();
        tmp[t] += u;
        __syncthreads();
    }
    if (i < N) excl[i] = tmp[t] - v;
    if (t == 255) bsum[b] = tmp[255];
}

__global__ __launch_bounds__(256) void scan_p2(const int* __restrict__ bsum, int nb,
                                               int* __restrict__ bbase, int* __restrict__ total) {
    __shared__ int tmp[256];
    int t = threadIdx.x;
    int run = 0;
    for (int base = 0; base < nb; base += 256) {
        int idx = base + t;
        int v = (idx < nb) ? bsum[idx] : 0;
        tmp[t] = v;
        __syncthreads();
        for (int o = 1; o < 256; o <<= 1) {
            int u = (t >= o) ? tmp[t - o] : 0;
            __syncthreads();
            tmp[t] += u;
            __syncthreads();
        }
        if (idx < nb) bbase[idx] = run + tmp[t] - v;
        run += tmp[255];
        __syncthreads();
    }
    if (t == 0) *total = run;
}

__global__ __launch_bounds__(256) void scan_p3(const int* __restrict__ excl, const int* __restrict__ bbase,
                                               const int* __restrict__ total, int N,
                                               int* __restrict__ offs, int* __restrict__ cursor) {
    int t = threadIdx.x, b = blockIdx.x, i = b * 256 + t;
    if (i < N) {
        int o = excl[i] + bbase[b];
        offs[i] = o;
        cursor[i] = o;
    }
    if (i == 0) offs[N] = *total;
}

__global__ __launch_bounds__(256) void scatter_kernel(const int* __restrict__ ei, int E, int N,
                                                      int* __restrict__ cursor, int* __restrict__ csr) {
    int i = blockIdx.x * 256 + threadIdx.x;
    if (i < E) {
        int d = ei[E + i];
        int p = atomicAdd(&cursor[d], 1);
        csr[p] = ei[i];
    } else if (i < E + N) {
        int n = i - E;
        int p = atomicAdd(&cursor[n], 1);
        csr[p] = n;
    }
}

// ---------------- pack W [K,256] f32 into MFMA B-fragment order (bf16) --------
__global__ __launch_bounds__(256) void packW_kernel(const float* __restrict__ W, int KS,
                                                    u16* __restrict__ out) {
    int idx = blockIdx.x * 256 + threadIdx.x;
    int total = 16 * KS * 512;
    if (idx >= total) return;
    int j = idx & 7;
    int lane = (idx >> 3) & 63;
    int rest = idx >> 9;        // ct*KS + ks
    int ks = rest % KS;
    int ct = rest / KS;
    int k = ks * 32 + (lane >> 4) * 8 + j;
    int n = ct * 16 + (lane & 15);
    out[idx] = f2bf(W[k * 256 + n]);
}

// ---------------- MFMA GEMM (32 rows/wave) + fused epilogue --------------------
// MODE 0: A = raw f32 [N,K] (layer 1 input x; converts to bf16 in-register)
// MODE 1: A = bf16 agg [N,256] with fused bn1-apply + relu (y1 never hits HBM)
// Epilogue: LDS transpose -> coalesced bf16 store + per-row al_s/al_d dots.
template <int K, int H, int MODE>
__global__ __launch_bounds__(256) void gemm_mfma(const void* __restrict__ Ain,
                                                 const u16* __restrict__ Bp,
                                                 u16* __restrict__ O,
                                                 const float* __restrict__ as_,
                                                 const float* __restrict__ ad_,
                                                 float* __restrict__ als,
                                                 float* __restrict__ ald,
                                                 const float* __restrict__ bsum,
                                                 const float* __restrict__ bsq,
                                                 const float* __restrict__ g,
                                                 const float* __restrict__ be,
                                                 int Nrows) {
    constexpr int KS = K / 32;
    __shared__ u16 lds[4][32 * 256];   // 64 KB/block
    __shared__ float sc_s[256], sh_s[256];
    if (MODE == 1) {  // bn1 scale/shift table (all threads reach the barrier)
        int t = threadIdx.x;
        float inv = 1.f / (float)Nrows;
        float mm = bsum[t] * inv;
        float vv = fmaxf(bsq[t] * inv - mm * mm, 0.f);
        float sc = rsqrtf(vv + 1e-5f) * g[t];
        sc_s[t] = sc;
        sh_s[t] = be[t] - mm * sc;
        __syncthreads();
    }
    int wave = threadIdx.x >> 6, lane = threadIdx.x & 63;
    int tile = blockIdx.x * 4 + wave;
    int row0 = tile * 32;
    if (row0 >= Nrows) return;
    int m = lane & 15, q = lane >> 4;
    int r0c = min(row0 + m, Nrows - 1);
    int r1c = min(row0 + 16 + m, Nrows - 1);

    bf16x8 af0[KS], af1[KS];
    if (MODE == 0) {
        const float* A = (const float*)Ain;
        const float* a0 = A + (size_t)r0c * K + q * 8;
        const float* a1 = A + (size_t)r1c * K + q * 8;
#pragma unroll
        for (int ks = 0; ks < KS; ks++) {
            af0[ks] = pack8(*(const float4*)(a0 + ks * 32), *(const float4*)(a0 + ks * 32 + 4));
            af1[ks] = pack8(*(const float4*)(a1 + ks * 32), *(const float4*)(a1 + ks * 32 + 4));
        }
    } else {
        const u16* A = (const u16*)Ain;
        const u16* a0 = A + (size_t)r0c * K + q * 8;
        const u16* a1 = A + (size_t)r1c * K + q * 8;
#pragma unroll
        for (int ks = 0; ks < KS; ks++) {
            int cb = ks * 32 + q * 8;
            float4 sc0 = *(const float4*)&sc_s[cb];
            float4 sc1 = *(const float4*)&sc_s[cb + 4];
            float4 sh0 = *(const float4*)&sh_s[cb];
            float4 sh1 = *(const float4*)&sh_s[cb + 4];
            ushort4 u0 = *(const ushort4*)(a0 + ks * 32);
            ushort4 u1 = *(const ushort4*)(a0 + ks * 32 + 4);
            float4 v0 = make_float4(fmaxf(fmaf(bf2f(u0.x), sc0.x, sh0.x), 0.f),
                                    fmaxf(fmaf(bf2f(u0.y), sc0.y, sh0.y), 0.f),
                                    fmaxf(fmaf(bf2f(u0.z), sc0.z, sh0.z), 0.f),
                                    fmaxf(fmaf(bf2f(u0.w), sc0.w, sh0.w), 0.f));
            float4 v1 = make_float4(fmaxf(fmaf(bf2f(u1.x), sc1.x, sh1.x), 0.f),
                                    fmaxf(fmaf(bf2f(u1.y), sc1.y, sh1.y), 0.f),
                                    fmaxf(fmaf(bf2f(u1.z), sc1.z, sh1.z), 0.f),
                                    fmaxf(fmaf(bf2f(u1.w), sc1.w, sh1.w), 0.f));
            af0[ks] = pack8(v0, v1);
            ushort4 w0 = *(const ushort4*)(a1 + ks * 32);
            ushort4 w1 = *(const ushort4*)(a1 + ks * 32 + 4);
            float4 x0 = make_float4(fmaxf(fmaf(bf2f(w0.x), sc0.x, sh0.x), 0.f),
                                    fmaxf(fmaf(bf2f(w0.y), sc0.y, sh0.y), 0.f),
                                    fmaxf(fmaf(bf2f(w0.z), sc0.z, sh0.z), 0.f),
                                    fmaxf(fmaf(bf2f(w0.w), sc0.w, sh0.w), 0.f));
            float4 x1 = make_float4(fmaxf(fmaf(bf2f(w1.x), sc1.x, sh1.x), 0.f),
                                    fmaxf(fmaf(bf2f(w1.y), sc1.y, sh1.y), 0.f),
                                    fmaxf(fmaf(bf2f(w1.z), sc1.z, sh1.z), 0.f),
                                    fmaxf(fmaf(bf2f(w1.w), sc1.w, sh1.w), 0.f));
            af1[ks] = pack8(x0, x1);
        }
    }

    u16* myl = lds[wave];
#pragma unroll
    for (int ct2 = 0; ct2 < 8; ct2++) {
        int ct0 = ct2 * 2;
        f32x4 a00 = {0.f, 0.f, 0.f, 0.f}, a01 = {0.f, 0.f, 0.f, 0.f};
        f32x4 a10 = {0.f, 0.f, 0.f, 0.f}, a11 = {0.f, 0.f, 0.f, 0.f};
        const u16* bp0 = Bp + ((size_t)(ct0 * KS) * 64 + lane) * 8;
        const u16* bp1 = bp0 + (size_t)KS * 512;
#pragma unroll
        for (int ks = 0; ks < KS; ks++) {   // 4 independent chains per B pair
            bf16x8 b0 = *(const bf16x8*)(bp0 + (size_t)ks * 512);
            bf16x8 b1 = *(const bf16x8*)(bp1 + (size_t)ks * 512);
            a00 = __builtin_amdgcn_mfma_f32_16x16x32_bf16(af0[ks], b0, a00, 0, 0, 0);
            a01 = __builtin_amdgcn_mfma_f32_16x16x32_bf16(af0[ks], b1, a01, 0, 0, 0);
            a10 = __builtin_amdgcn_mfma_f32_16x16x32_bf16(af1[ks], b0, a10, 0, 0, 0);
            a11 = __builtin_amdgcn_mfma_f32_16x16x32_bf16(af1[ks], b1, a11, 0, 0, 0);
        }
        // C/D layout: col = lane&15, row = (lane>>4)*4 + r   [verified m89]
#pragma unroll
        for (int r = 0; r < 4; r++) {
            myl[(q * 4 + r) * 256 + ct0 * 16 + m] = f2bf(a00[r]);
            myl[(q * 4 + r) * 256 + ct0 * 16 + 16 + m] = f2bf(a01[r]);
            myl[(16 + q * 4 + r) * 256 + ct0 * 16 + m] = f2bf(a10[r]);
            myl[(16 + q * 4 + r) * 256 + ct0 * 16 + 16 + m] = f2bf(a11[r]);
        }
    }
    // epilogue: coalesced store + al dot (same-wave LDS, no barrier needed)
    int c8 = (lane & 31) * 8;
    float4 s0 = *(const float4*)(as_ + c8);
    float4 s1 = *(const float4*)(as_ + c8 + 4);
    float4 d0 = *(const float4*)(ad_ + c8);
    float4 d1 = *(const float4*)(ad_ + c8 + 4);
#pragma unroll
    for (int p = 0; p < 16; p++) {
        int row = p * 2 + (lane >> 5);
        if (row0 + row >= Nrows) continue;
        int4 v = *(const int4*)&myl[row * 256 + c8];
        *(int4*)&O[(size_t)(row0 + row) * 256 + c8] = v;
        float f0 = bf2f((u16)(v.x & 0xffff)), f1 = bf2f((u16)((unsigned)v.x >> 16));
        float f2 = bf2f((u16)(v.y & 0xffff)), f3 = bf2f((u16)((unsigned)v.y >> 16));
        float f4 = bf2f((u16)(v.z & 0xffff)), f5 = bf2f((u16)((unsigned)v.z >> 16));
        float f6 = bf2f((u16)(v.w & 0xffff)), f7 = bf2f((u16)((unsigned)v.w >> 16));
        float ps = f0 * s0.x + f1 * s0.y + f2 * s0.z + f3 * s0.w +
                   f4 * s1.x + f5 * s1.y + f6 * s1.z + f7 * s1.w;
        float pd = f0 * d0.x + f1 * d0.y + f2 * d0.z + f3 * d0.w +
                   f4 * d1.x + f5 * d1.y + f6 * d1.z + f7 * d1.w;
        const int W = (H == 4) ? 8 : 32;
#pragma unroll
        for (int o = 1; o < W; o <<= 1) {
            ps += __shfl_xor(ps, o);
            pd += __shfl_xor(pd, o);
        }
        if (H == 4) {
            if ((lane & 7) == 0) {
                int head = (lane & 31) >> 3;
                als[(row0 + row) * 4 + head] = ps;
                ald[(row0 + row) * 4 + head] = pd;
            }
        } else {
            if ((lane & 31) == 0) {
                als[row0 + row] = ps;
                ald[row0 + row] = pd;
            }
        }
    }
}

// ---------------- fused GAT softmax + accumulate + BN-stats (atomic-free LDS) -
// Half-wave (32 lanes) per dst node; lane covers 8 cols via one int4 load.
// Stats: each thread writes acc[8] to a PRIVATE racc slot (plain ds_write,
// no LDS atomics — round 13's ds_add_f32 hit 4 banks 16-way serialized and
// cost 160us), one barrier, then thread t reduces column t over the 8
// half-waves (conflict-free reads) and issues 2 global atomics.
template <int H>
__global__ __launch_bounds__(256) void gat_fused_kernel(const int* __restrict__ offs,
                                                        const int* __restrict__ csr,
                                                        const float* __restrict__ als,
                                                        const float* __restrict__ ald,
                                                        const u16* __restrict__ h,
                                                        u16* __restrict__ out,
                                                        float* __restrict__ gsum,
                                                        float* __restrict__ gsq, int N) {
    __shared__ float lalpha[8][32 * H];
    __shared__ int lsrc[8][32];
    __shared__ float racc[8][256];
    int t = threadIdx.x;
    int hw = t >> 5;          // half-wave in block (0..7)
    int lane = t & 31;        // lane within half-wave
    int w = (blockIdx.x * 256 + t) >> 5;
    float acc[8];
#pragma unroll
    for (int k2 = 0; k2 < 8; k2++) acc[k2] = 0.f;
    if (w < N) {
        int s0 = offs[w], s1 = offs[w + 1];
        float adl[H], e0[H], m[H], den[H];
#pragma unroll
        for (int hh = 0; hh < H; hh++) { adl[hh] = ald[w * H + hh]; m[hh] = -1e30f; }
        int i0 = s0 + lane;
        bool have = (i0 < s1);
        int src0 = 0;
        if (have) {
            src0 = csr[i0];
            if (H == 4) {
                float4 av = ((const float4*)als)[src0];
                float tmp[4] = {av.x, av.y, av.z, av.w};
#pragma unroll
                for (int hh = 0; hh < 4; hh++) {
                    float e = tmp[hh] + adl[hh];
                    e = e > 0.f ? e : 0.2f * e;
                    e0[hh] = e; m[hh] = e;
                }
            } else {
                float e = als[src0] + adl[0];
                e = e > 0.f ? e : 0.2f * e;
                e0[0] = e; m[0] = e;
            }
        }
        for (int i = i0 + 32; i < s1; i += 32) {  // rare: deg > 32
            int s = csr[i];
#pragma unroll
            for (int hh = 0; hh < H; hh++) {
                float e = als[s * H + hh] + adl[hh];
                e = e > 0.f ? e : 0.2f * e;
                m[hh] = fmaxf(m[hh], e);
            }
        }
#pragma unroll
        for (int hh = 0; hh < H; hh++)
            for (int o = 16; o; o >>= 1) m[hh] = fmaxf(m[hh], __shfl_xor(m[hh], o));
#pragma unroll
        for (int hh = 0; hh < H; hh++) den[hh] = have ? __expf(e0[hh] - m[hh]) : 0.f;
        for (int i = i0 + 32; i < s1; i += 32) {
            int s = csr[i];
#pragma unroll
            for (int hh = 0; hh < H; hh++) {
                float e = als[s * H + hh] + adl[hh];
                e = e > 0.f ? e : 0.2f * e;
                den[hh] += __expf(e - m[hh]);
            }
        }
#pragma unroll
        for (int hh = 0; hh < H; hh++)
            for (int o = 16; o; o >>= 1) den[hh] += __shfl_xor(den[hh], o);
        float rden[H];
#pragma unroll
        for (int hh = 0; hh < H; hh++) rden[hh] = 1.f / (den[hh] + 1e-16f);
        // park chunk-0 alpha/src in per-half-wave LDS (same-wave DS order)
        if (have) {
            lsrc[hw][lane] = src0;
#pragma unroll
            for (int hh = 0; hh < H; hh++)
                lalpha[hw][lane * H + hh] = __expf(e0[hh] - m[hh]) * rden[hh];
        }
        int deg = s1 - s0;
        int cend = min(deg, 32);
        int myh = (H == 4) ? (lane >> 3) : 0;   // head = (lane*8)/64
        const int4* h16 = (const int4*)h;       // 32 int4 per 256-col row
        const float* la = lalpha[hw];
        const int* ls = lsrc[hw];
        int i = 0;
        for (; i + 4 <= cend; i += 4) {
            int sa = ls[i], sb = ls[i + 1], sc = ls[i + 2], sd = ls[i + 3];
            float aa = la[i * H + myh];
            float ab = la[(i + 1) * H + myh];
            float ac = la[(i + 2) * H + myh];
            float ad = la[(i + 3) * H + myh];
            int4 ha = h16[(size_t)sa * 32 + lane];
            int4 hb = h16[(size_t)sb * 32 + lane];
            int4 hc = h16[(size_t)sc * 32 + lane];
            int4 hd = h16[(size_t)sd * 32 + lane];
            fma8(acc, aa, ha);
            fma8(acc, ab, hb);
            fma8(acc, ac, hc);
            fma8(acc, ad, hd);
        }
        for (; i < cend; i++) {
            int s = ls[i];
            float a = la[i * H + myh];
            fma8(acc, a, h16[(size_t)s * 32 + lane]);
        }
        for (int j = s0 + 32; j < s1; j++) {  // rare deg>32 tail: recompute alpha
            int s = csr[j];
            float e = als[s * H + myh] + adl[myh];
            e = e > 0.f ? e : 0.2f * e;
            float a = __expf(e - m[myh]) * rden[myh];
            fma8(acc, a, h16[(size_t)s * 32 + lane]);
        }
        int4 o;
        o.x = (int)((unsigned)f2bf(acc[0]) | ((unsigned)f2bf(acc[1]) << 16));
        o.y = (int)((unsigned)f2bf(acc[2]) | ((unsigned)f2bf(acc[3]) << 16));
        o.z = (int)((unsigned)f2bf(acc[4]) | ((unsigned)f2bf(acc[5]) << 16));
        o.w = (int)((unsigned)f2bf(acc[6]) | ((unsigned)f2bf(acc[7]) << 16));
        ((int4*)out)[(size_t)w * 32 + lane] = o;
    }
    // per-block stats: private LDS slots (no atomics), then column reduce
    float4* rp = (float4*)&racc[hw][lane * 8];
    rp[0] = make_float4(acc[0], acc[1], acc[2], acc[3]);
    rp[1] = make_float4(acc[4], acc[5], acc[6], acc[7]);
    __syncthreads();
    float sv = 0.f, qv = 0.f;
#pragma unroll
    for (int hh = 0; hh < 8; hh++) {
        float v = racc[hh][t];
        sv += v;
        qv = fmaf(v, v, qv);
    }
    atomicAdd(&gsum[t], sv);
    atomicAdd(&gsq[t], qv);
}

// layer 2: bn-apply + relu + fused global-mean-pool (batch sorted)
__global__ __launch_bounds__(256) void bn_apply_pool(const u16* __restrict__ agg,
                                                     const float* __restrict__ sum,
                                                     const float* __restrict__ sq,
                                                     const float* __restrict__ g,
                                                     const float* __restrict__ be,
                                                     const int* __restrict__ batch,
                                                     u16* __restrict__ out,
                                                     float* __restrict__ pools,
                                                     int* __restrict__ cnt, int N) {
    int t = threadIdx.x;
    float inv = 1.f / (float)N;
    float mm = sum[t] * inv;
    float vv = fmaxf(sq[t] * inv - mm * mm, 0.f);
    float sc = rsqrtf(vv + 1e-5f) * g[t];
    float sh = be[t] - mm * sc;
    int rows = (N + gridDim.x - 1) / gridDim.x;
    int r0 = blockIdx.x * rows, r1 = min(r0 + rows, N);
    if (r0 >= r1) return;
    float acc = 0.f;
    int cur = batch[r0], c0 = 0;
    for (int r = r0; r < r1; r++) {
        int b = batch[r];  // wave-uniform scalar load
        if (b != cur) {
            atomicAdd(&pools[cur * 256 + t], acc);
            if (t == 0) atomicAdd(&cnt[cur], c0);
            acc = 0.f; c0 = 0; cur = b;
        }
        float v = bf2f(agg[(size_t)r * 256 + t]);
        float y = fmaxf(fmaf(v, sc, sh), 0.f);
        out[(size_t)r * 256 + t] = f2bf(y);
        acc += y; c0++;
    }
    atomicAdd(&pools[cur * 256 + t], acc);
    if (t == 0) atomicAdd(&cnt[cur], c0);
}

// shared = relu(gf @ W_sh + b_sh) fused with heads; one block per graph
__global__ __launch_bounds__(256) void shared_head_kernel(const float* __restrict__ pools,
                                                          const int* __restrict__ cnt,
                                                          const float* __restrict__ Wsh,
                                                          const float* __restrict__ bsh,
                                                          const float* __restrict__ Wnode,
                                                          const float* __restrict__ Wcrit,
                                                          const float* __restrict__ bcrit,
                                                          const float* __restrict__ Wtype,
                                                          const float* __restrict__ btype,
                                                          const u16* __restrict__ xn,
                                                          const int* __restrict__ tgt,
                                                          float* __restrict__ gdot,
                                                          float* __restrict__ out_tail) {
    __shared__ float gf[256], red[256];
    int b = blockIdx.x, t = threadIdx.x;
    gf[t] = pools[b * 256 + t] / fmaxf((float)cnt[b], 1.f);
    __syncthreads();
    float acc = bsh[t];
    for (int k = 0; k < 256; k++) acc = fmaf(gf[k], Wsh[k * 256 + t], acc);
    float s = fmaxf(acc, 0.f);
    int tn = tgt[b];
    float xnt = bf2f(xn[(size_t)tn * 256 + t]);
    float pg = s * Wnode[256 + t];
    float pv = s * Wcrit[t];
    float pt0 = s * Wtype[t * 4 + 0] + xnt * Wtype[(256 + t) * 4 + 0];
    float pt1 = s * Wtype[t * 4 + 1] + xnt * Wtype[(256 + t) * 4 + 1];
    float pt2 = s * Wtype[t * 4 + 2] + xnt * Wtype[(256 + t) * 4 + 2];
    float pt3 = s * Wtype[t * 4 + 3] + xnt * Wtype[(256 + t) * 4 + 3];
    auto bred = [&](float v) -> float {
        __syncthreads();
        red[t] = v;
        __syncthreads();
        for (int o = 128; o; o >>= 1) {
            if (t < o) red[t] += red[t + o];
            __syncthreads();
        }
        return red[0];
    };
    float rg = bred(pg);
    float rv = bred(pv);
    float r0 = bred(pt0);
    float r1 = bred(pt1);
    float r2 = bred(pt2);
    float r3 = bred(pt3);
    if (t == 0) {
        gdot[b] = rg;
        out_tail[32 + b] = rv + bcrit[0];
        out_tail[b * 4 + 0] = r0 + btype[0];
        out_tail[b * 4 + 1] = r1 + btype[1];
        out_tail[b * 4 + 2] = r2 + btype[2];
        out_tail[b * 4 + 3] = r3 + btype[3];
    }
}

// node_scores: one wave per node (bf16 x_nodes)
__global__ __launch_bounds__(256) void node_scores_kernel(const u16* __restrict__ xn,
                                                          const float* __restrict__ Wnode, const float* __restrict__ bnode,
                                                          const int* __restrict__ batch, const float* __restrict__ gdot,
                                                          float* __restrict__ out, int N) {
    int w = (blockIdx.x * 256 + threadIdx.x) >> 6;
    int lane = threadIdx.x & 63;
    if (w >= N) return;
    ushort4 xv = ((const ushort4*)(xn + (size_t)w * 256))[lane];
    float4 wv = ((const float4*)Wnode)[lane];
    float p = bf2f(xv.x) * wv.x + bf2f(xv.y) * wv.y + bf2f(xv.z) * wv.z + bf2f(xv.w) * wv.w;
    for (int o = 32; o; o >>= 1) p += __shfl_xor(p, o);
    if (lane == 0) out[w] = p + gdot[batch[w]] + bnode[0];
}

extern "C" void kernel_launch(void* const* d_in, const int* in_sizes, int n_in,
                              void* d_out, int out_size, void* d_ws, size_t ws_size,
                              hipStream_t stream) {
    const float* x = (const float*)d_in[0];
    const int* ei = (const int*)d_in[1];
    const int* batch = (const int*)d_in[2];
    const int* tgt = (const int*)d_in[3];
    const float* W1 = (const float*)d_in[4];
    const float* a1s = (const float*)d_in[5];
    const float* a1d = (const float*)d_in[6];
    // b1 (d_in[7]) / b2 (d_in[11]): constant column shifts cancel exactly in BatchNorm
    const float* W2 = (const float*)d_in[8];
    const float* a2s = (const float*)d_in[9];
    const float* a2d = (const float*)d_in[10];
    const float* g1 = (const float*)d_in[12];
    const float* be1 = (const float*)d_in[13];
    const float* g2 = (const float*)d_in[14];
    const float* be2 = (const float*)d_in[15];
    const float* Wsh = (const float*)d_in[16];
    const float* bsh = (const float*)d_in[17];
    const float* Wnode = (const float*)d_in[18];
    const float* bnode = (const float*)d_in[19];
    const float* Wtype = (const float*)d_in[20];
    const float* btype = (const float*)d_in[21];
    const float* Wcrit = (const float*)d_in[22];
    const float* bcrit = (const float*)d_in[23];

    const int N = in_sizes[2];
    const int E = in_sizes[1] / 2;
    const int Et = E + N;
    const int nb = (N + 255) / 256;   // scan blocks

    // ---- workspace carve (~85 MB) ----
    char* w = (char*)d_ws;
    size_t off = 0;
    auto carve = [&](size_t bytes) -> char* {
        char* p = w + off;
        off = (off + bytes + 255) & ~(size_t)255;
        return p;
    };
    u16* agg_bf = (u16*)carve((size_t)N * 256 * 2);    // bf16 aggregation (both layers)
    u16* h_bf = (u16*)carve((size_t)N * 256 * 2);      // h1 -> h2 (gemm outputs)
    u16* y_bf = (u16*)carve((size_t)N * 256 * 2);      // x_nodes (bn2 out)
    u16* W1p = (u16*)carve(16 * 2 * 512 * 2);          // packed W1 frags
    u16* W2p = (u16*)carve(16 * 8 * 512 * 2);          // packed W2 frags
    float* al1s = (float*)carve((size_t)N * 4 * 4);
    float* al1d = (float*)carve((size_t)N * 4 * 4);
    float* al2s = (float*)carve((size_t)N * 4);
    float* al2d = (float*)carve((size_t)N * 4);
    int* offs = (int*)carve((size_t)(N + 1) * 4);
    int* cursor = (int*)carve((size_t)N * 4);
    int* csr = (int*)carve((size_t)Et * 4);
    int* excl = (int*)carve((size_t)N * 4);
    int* bsum = (int*)carve((size_t)nb * 4);
    int* bbase = (int*)carve((size_t)nb * 4);
    int* stotal = (int*)carve(64);
    float* gdot = (float*)carve(64);
    char* zero0 = w + off;
    int* counts = (int*)carve((size_t)N * 4);
    float* bn1s = (float*)carve(1024);
    float* bn1q = (float*)carve(1024);
    float* bn2s = (float*)carve(1024);
    float* bn2q = (float*)carve(1024);
    float* pools = (float*)carve(8 * 256 * 4);
    int* cnt = (int*)carve(64);
    size_t zbytes = (size_t)((w + off) - zero0);
    hipMemsetAsync(zero0, 0, zbytes, stream);

    int wavesPerGrid = (N + 3) / 4;                  // 4 node-waves per 256-thread block
    int halfGrid = (N + 7) / 8;                      // 8 node-half-waves per block
    int mfmaGrid = (((N + 31) / 32) + 3) / 4;        // 4 32-row tiles (waves) per block

    // ---- CSR build (3-phase parallel scan) + weight prep ----
    hist_kernel<<<(Et + 255) / 256, 256, 0, stream>>>(ei, E, N, counts);
    scan_p1<<<nb, 256, 0, stream>>>(counts, N, excl, bsum);
    scan_p2<<<1, 256, 0, stream>>>(bsum, nb, bbase, stotal);
    scan_p3<<<nb, 256, 0, stream>>>(excl, bbase, stotal, N, offs, cursor);
    scatter_kernel<<<(Et + 255) / 256, 256, 0, stream>>>(ei, E, N, cursor, csr);
    packW_kernel<<<(16 * 2 * 512 + 255) / 256, 256, 0, stream>>>(W1, 2, W1p);
    packW_kernel<<<(16 * 8 * 512 + 255) / 256, 256, 0, stream>>>(W2, 8, W2p);

    // ---- layer 1: GAT(4 heads); x converted to bf16 in gemm A-load ----
    gemm_mfma<64, 4, 0><<<mfmaGrid, 256, 0, stream>>>(x, W1p, h_bf, a1s, a1d, al1s, al1d,
                                                      bn1s, bn1q, g1, be1, N);
    gat_fused_kernel<4><<<halfGrid, 256, 0, stream>>>(offs, csr, al1s, al1d, h_bf, agg_bf,
                                                      bn1s, bn1q, N);

    // ---- layer 2: bn1-apply fused into gemm A-load; GAT(1) + BN2 + pool ----
    gemm_mfma<256, 1, 1><<<mfmaGrid, 256, 0, stream>>>(agg_bf, W2p, h_bf, a2s, a2d, al2s, al2d,
                                                       bn1s, bn1q, g1, be1, N);
    gat_fused_kernel<1><<<halfGrid, 256, 0, stream>>>(offs, csr, al2s, al2d, h_bf, agg_bf,
                                                      bn2s, bn2q, N);
    bn_apply_pool<<<1024, 256, 0, stream>>>(agg_bf, bn2s, bn2q, g2, be2, batch, y_bf, pools, cnt, N);

    // ---- heads ----
    shared_head_kernel<<<8, 256, 0, stream>>>(pools, cnt, Wsh, bsh, Wnode, Wcrit, bcrit,
                                              Wtype, btype, y_bf, tgt, gdot, (float*)d_out + N);
    node_scores_kernel<<<wavesPerGrid, 256, 0, stream>>>(y_bf, Wnode, bnode, batch, gdot,
                                                         (float*)d_out, N);
}

// Round 15
// 396.285 us; speedup vs baseline: 1.5900x; 1.4370x over previous
//
#include <hip/hip_runtime.h>

typedef unsigned short u16;
typedef __attribute__((ext_vector_type(8))) short bf16x8;   // 8 bf16 = 4 VGPRs
typedef __attribute__((ext_vector_type(4))) float f32x4;

__device__ __forceinline__ float bf2f(u16 u) {
    return __uint_as_float(((unsigned int)u) << 16);
}
__device__ __forceinline__ u16 f2bf(float f) {
    unsigned int u = __float_as_uint(f);
    u += 0x7fffu + ((u >> 16) & 1u);
    return (u16)(u >> 16);
}
__device__ __forceinline__ bf16x8 pack8(float4 a, float4 b) {
    bf16x8 r;
    r[0] = (short)f2bf(a.x); r[1] = (short)f2bf(a.y);
    r[2] = (short)f2bf(a.z); r[3] = (short)f2bf(a.w);
    r[4] = (short)f2bf(b.x); r[5] = (short)f2bf(b.y);
    r[6] = (short)f2bf(b.z); r[7] = (short)f2bf(b.w);
    return r;
}
// fma 8 bf16 lanes (packed in int4) into acc[8]
__device__ __forceinline__ void fma8(float* acc, float a, int4 v) {
    unsigned vx = (unsigned)v.x, vy = (unsigned)v.y, vz = (unsigned)v.z, vw = (unsigned)v.w;
    acc[0] = fmaf(a, bf2f((u16)(vx & 0xffff)), acc[0]);
    acc[1] = fmaf(a, bf2f((u16)(vx >> 16)), acc[1]);
    acc[2] = fmaf(a, bf2f((u16)(vy & 0xffff)), acc[2]);
    acc[3] = fmaf(a, bf2f((u16)(vy >> 16)), acc[3]);
    acc[4] = fmaf(a, bf2f((u16)(vz & 0xffff)), acc[4]);
    acc[5] = fmaf(a, bf2f((u16)(vz >> 16)), acc[5]);
    acc[6] = fmaf(a, bf2f((u16)(vw & 0xffff)), acc[6]);
    acc[7] = fmaf(a, bf2f((u16)(vw >> 16)), acc[7]);
}

// ---------------- CSR build (dst-indexed), reused by both GAT layers ----------
__global__ __launch_bounds__(256) void hist_kernel(const int* __restrict__ ei, int E, int N,
                                                   int* __restrict__ counts) {
    int i = blockIdx.x * 256 + threadIdx.x;
    if (i < E) atomicAdd(&counts[ei[E + i]], 1);
    else if (i < E + N) atomicAdd(&counts[i - E], 1);
}

// ---- 3-phase parallel exclusive scan over counts[N] -> offs[N+1], cursor[N] --
__global__ __launch_bounds__(256) void scan_p1(const int* __restrict__ counts, int N,
                                               int* __restrict__ excl, int* __restrict__ bsum) {
    __shared__ int tmp[256];
    int t = threadIdx.x, b = blockIdx.x, i = b * 256 + t;
    int v = (i < N) ? counts[i] : 0;
    tmp[t] = v;
    __syncthreads();
    for (int o = 1; o < 256; o <<= 1) {
        int u = (t >= o) ? tmp[t - o] : 0;
        __syncthreads();
        tmp[t] += u;
        __syncthreads();
    }
    if (i < N) excl[i] = tmp[t] - v;
    if (t == 255) bsum[b] = tmp[255];
}

__global__ __launch_bounds__(256) void scan_p2(const int* __restrict__ bsum, int nb,
                                               int* __restrict__ bbase, int* __restrict__ total) {
    __shared__ int tmp[256];
    int t = threadIdx.x;
    int run = 0;
    for (int base = 0; base < nb; base += 256) {
        int idx = base + t;
        int v = (idx < nb) ? bsum[idx] : 0;
        tmp[t] = v;
        __syncthreads();
        for (int o = 1; o < 256; o <<= 1) {
            int u = (t >= o) ? tmp[t - o] : 0;
            __syncthreads();
            tmp[t] += u;
            __syncthreads();
        }
        if (idx < nb) bbase[idx] = run + tmp[t] - v;
        run += tmp[255];
        __syncthreads();
    }
    if (t == 0) *total = run;
}

__global__ __launch_bounds__(256) void scan_p3(const int* __restrict__ excl, const int* __restrict__ bbase,
                                               const int* __restrict__ total, int N,
                                               int* __restrict__ offs, int* __restrict__ cursor) {
    int t = threadIdx.x, b = blockIdx.x, i = b * 256 + t;
    if (i < N) {
        int o = excl[i] + bbase[b];
        offs[i] = o;
        cursor[i] = o;
    }
    if (i == 0) offs[N] = *total;
}

__global__ __launch_bounds__(256) void scatter_kernel(const int* __restrict__ ei, int E, int N,
                                                      int* __restrict__ cursor, int* __restrict__ csr) {
    int i = blockIdx.x * 256 + threadIdx.x;
    if (i < E) {
        int d = ei[E + i];
        int p = atomicAdd(&cursor[d], 1);
        csr[p] = ei[i];
    } else if (i < E + N) {
        int n = i - E;
        int p = atomicAdd(&cursor[n], 1);
        csr[p] = n;
    }
}

// ------- pack W1 [64,256] + W2 [256,256] f32 into MFMA B-fragment order -------
// (single dispatch for both weights)
__global__ __launch_bounds__(256) void packW_both_kernel(const float* __restrict__ W1,
                                                         const float* __restrict__ W2,
                                                         u16* __restrict__ out1,
                                                         u16* __restrict__ out2) {
    const int total1 = 16 * 2 * 512;    // KS=2
    const int total2 = 16 * 8 * 512;    // KS=8
    int idx = blockIdx.x * 256 + threadIdx.x;
    const float* W;
    u16* out;
    int KS, id;
    if (idx < total1) { W = W1; out = out1; KS = 2; id = idx; }
    else if (idx < total1 + total2) { W = W2; out = out2; KS = 8; id = idx - total1; }
    else return;
    int j = id & 7;
    int lane = (id >> 3) & 63;
    int rest = id >> 9;        // ct*KS + ks
    int ks = rest % KS;
    int ct = rest / KS;
    int k = ks * 32 + (lane >> 4) * 8 + j;
    int n = ct * 16 + (lane & 15);
    out[id] = f2bf(W[k * 256 + n]);
}

// ---------------- MFMA GEMM (32 rows/wave) + fused epilogue --------------------
// MODE 0: A = raw f32 [N,K] (layer 1 input x; converts to bf16 in-register)
// MODE 1: A = bf16 agg [N,256] with fused bn1-apply + relu (y1 never hits HBM)
// Epilogue: LDS transpose -> coalesced bf16 store + per-row al_s/al_d dots.
template <int K, int H, int MODE>
__global__ __launch_bounds__(256) void gemm_mfma(const void* __restrict__ Ain,
                                                 const u16* __restrict__ Bp,
                                                 u16* __restrict__ O,
                                                 const float* __restrict__ as_,
                                                 const float* __restrict__ ad_,
                                                 float* __restrict__ als,
                                                 float* __restrict__ ald,
                                                 const float* __restrict__ bsum,
                                                 const float* __restrict__ bsq,
                                                 const float* __restrict__ g,
                                                 const float* __restrict__ be,
                                                 int Nrows) {
    constexpr int KS = K / 32;
    __shared__ u16 lds[4][32 * 256];   // 64 KB/block
    __shared__ float sc_s[256], sh_s[256];
    if (MODE == 1) {  // bn1 scale/shift table (all threads reach the barrier)
        int t = threadIdx.x;
        float inv = 1.f / (float)Nrows;
        float mm = bsum[t] * inv;
        float vv = fmaxf(bsq[t] * inv - mm * mm, 0.f);
        float sc = rsqrtf(vv + 1e-5f) * g[t];
        sc_s[t] = sc;
        sh_s[t] = be[t] - mm * sc;
        __syncthreads();
    }
    int wave = threadIdx.x >> 6, lane = threadIdx.x & 63;
    int tile = blockIdx.x * 4 + wave;
    int row0 = tile * 32;
    if (row0 >= Nrows) return;
    int m = lane & 15, q = lane >> 4;
    int r0c = min(row0 + m, Nrows - 1);
    int r1c = min(row0 + 16 + m, Nrows - 1);

    bf16x8 af0[KS], af1[KS];
    if (MODE == 0) {
        const float* A = (const float*)Ain;
        const float* a0 = A + (size_t)r0c * K + q * 8;
        const float* a1 = A + (size_t)r1c * K + q * 8;
#pragma unroll
        for (int ks = 0; ks < KS; ks++) {
            af0[ks] = pack8(*(const float4*)(a0 + ks * 32), *(const float4*)(a0 + ks * 32 + 4));
            af1[ks] = pack8(*(const float4*)(a1 + ks * 32), *(const float4*)(a1 + ks * 32 + 4));
        }
    } else {
        const u16* A = (const u16*)Ain;
        const u16* a0 = A + (size_t)r0c * K + q * 8;
        const u16* a1 = A + (size_t)r1c * K + q * 8;
#pragma unroll
        for (int ks = 0; ks < KS; ks++) {
            int cb = ks * 32 + q * 8;
            float4 sc0 = *(const float4*)&sc_s[cb];
            float4 sc1 = *(const float4*)&sc_s[cb + 4];
            float4 sh0 = *(const float4*)&sh_s[cb];
            float4 sh1 = *(const float4*)&sh_s[cb + 4];
            ushort4 u0 = *(const ushort4*)(a0 + ks * 32);
            ushort4 u1 = *(const ushort4*)(a0 + ks * 32 + 4);
            float4 v0 = make_float4(fmaxf(fmaf(bf2f(u0.x), sc0.x, sh0.x), 0.f),
                                    fmaxf(fmaf(bf2f(u0.y), sc0.y, sh0.y), 0.f),
                                    fmaxf(fmaf(bf2f(u0.z), sc0.z, sh0.z), 0.f),
                                    fmaxf(fmaf(bf2f(u0.w), sc0.w, sh0.w), 0.f));
            float4 v1 = make_float4(fmaxf(fmaf(bf2f(u1.x), sc1.x, sh1.x), 0.f),
                                    fmaxf(fmaf(bf2f(u1.y), sc1.y, sh1.y), 0.f),
                                    fmaxf(fmaf(bf2f(u1.z), sc1.z, sh1.z), 0.f),
                                    fmaxf(fmaf(bf2f(u1.w), sc1.w, sh1.w), 0.f));
            af0[ks] = pack8(v0, v1);
            ushort4 w0 = *(const ushort4*)(a1 + ks * 32);
            ushort4 w1 = *(const ushort4*)(a1 + ks * 32 + 4);
            float4 x0 = make_float4(fmaxf(fmaf(bf2f(w0.x), sc0.x, sh0.x), 0.f),
                                    fmaxf(fmaf(bf2f(w0.y), sc0.y, sh0.y), 0.f),
                                    fmaxf(fmaf(bf2f(w0.z), sc0.z, sh0.z), 0.f),
                                    fmaxf(fmaf(bf2f(w0.w), sc0.w, sh0.w), 0.f));
            float4 x1 = make_float4(fmaxf(fmaf(bf2f(w1.x), sc1.x, sh1.x), 0.f),
                                    fmaxf(fmaf(bf2f(w1.y), sc1.y, sh1.y), 0.f),
                                    fmaxf(fmaf(bf2f(w1.z), sc1.z, sh1.z), 0.f),
                                    fmaxf(fmaf(bf2f(w1.w), sc1.w, sh1.w), 0.f));
            af1[ks] = pack8(x0, x1);
        }
    }

    u16* myl = lds[wave];
#pragma unroll
    for (int ct2 = 0; ct2 < 8; ct2++) {
        int ct0 = ct2 * 2;
        f32x4 a00 = {0.f, 0.f, 0.f, 0.f}, a01 = {0.f, 0.f, 0.f, 0.f};
        f32x4 a10 = {0.f, 0.f, 0.f, 0.f}, a11 = {0.f, 0.f, 0.f, 0.f};
        const u16* bp0 = Bp + ((size_t)(ct0 * KS) * 64 + lane) * 8;
        const u16* bp1 = bp0 + (size_t)KS * 512;
#pragma unroll
        for (int ks = 0; ks < KS; ks++) {   // 4 independent chains per B pair
            bf16x8 b0 = *(const bf16x8*)(bp0 + (size_t)ks * 512);
            bf16x8 b1 = *(const bf16x8*)(bp1 + (size_t)ks * 512);
            a00 = __builtin_amdgcn_mfma_f32_16x16x32_bf16(af0[ks], b0, a00, 0, 0, 0);
            a01 = __builtin_amdgcn_mfma_f32_16x16x32_bf16(af0[ks], b1, a01, 0, 0, 0);
            a10 = __builtin_amdgcn_mfma_f32_16x16x32_bf16(af1[ks], b0, a10, 0, 0, 0);
            a11 = __builtin_amdgcn_mfma_f32_16x16x32_bf16(af1[ks], b1, a11, 0, 0, 0);
        }
        // C/D layout: col = lane&15, row = (lane>>4)*4 + r   [verified m89]
#pragma unroll
        for (int r = 0; r < 4; r++) {
            myl[(q * 4 + r) * 256 + ct0 * 16 + m] = f2bf(a00[r]);
            myl[(q * 4 + r) * 256 + ct0 * 16 + 16 + m] = f2bf(a01[r]);
            myl[(16 + q * 4 + r) * 256 + ct0 * 16 + m] = f2bf(a10[r]);
            myl[(16 + q * 4 + r) * 256 + ct0 * 16 + 16 + m] = f2bf(a11[r]);
        }
    }
    // epilogue: coalesced store + al dot (same-wave LDS, no barrier needed)
    int c8 = (lane & 31) * 8;
    float4 s0 = *(const float4*)(as_ + c8);
    float4 s1 = *(const float4*)(as_ + c8 + 4);
    float4 d0 = *(const float4*)(ad_ + c8);
    float4 d1 = *(const float4*)(ad_ + c8 + 4);
#pragma unroll
    for (int p = 0; p < 16; p++) {
        int row = p * 2 + (lane >> 5);
        if (row0 + row >= Nrows) continue;
        int4 v = *(const int4*)&myl[row * 256 + c8];
        *(int4*)&O[(size_t)(row0 + row) * 256 + c8] = v;
        float f0 = bf2f((u16)(v.x & 0xffff)), f1 = bf2f((u16)((unsigned)v.x >> 16));
        float f2 = bf2f((u16)(v.y & 0xffff)), f3 = bf2f((u16)((unsigned)v.y >> 16));
        float f4 = bf2f((u16)(v.z & 0xffff)), f5 = bf2f((u16)((unsigned)v.z >> 16));
        float f6 = bf2f((u16)(v.w & 0xffff)), f7 = bf2f((u16)((unsigned)v.w >> 16));
        float ps = f0 * s0.x + f1 * s0.y + f2 * s0.z + f3 * s0.w +
                   f4 * s1.x + f5 * s1.y + f6 * s1.z + f7 * s1.w;
        float pd = f0 * d0.x + f1 * d0.y + f2 * d0.z + f3 * d0.w +
                   f4 * d1.x + f5 * d1.y + f6 * d1.z + f7 * d1.w;
        const int W = (H == 4) ? 8 : 32;
#pragma unroll
        for (int o = 1; o < W; o <<= 1) {
            ps += __shfl_xor(ps, o);
            pd += __shfl_xor(pd, o);
        }
        if (H == 4) {
            if ((lane & 7) == 0) {
                int head = (lane & 31) >> 3;
                als[(row0 + row) * 4 + head] = ps;
                ald[(row0 + row) * 4 + head] = pd;
            }
        } else {
            if ((lane & 31) == 0) {
                als[row0 + row] = ps;
                ald[row0 + row] = pd;
            }
        }
    }
}

// ---------------- fused GAT softmax + accumulate (HALF-wave per dst) ----------
// 2 nodes per wave: 32 lanes per node, each lane covers 8 cols via one int4
// load. NO stats fusion: rounds 13/14 showed the per-block stats flush
// (512 atomics x 6250 blocks onto 32 cache lines) serializes in L2 and costs
// >120us. Separate 1024-block bn_stats has 16x less per-line contention.
template <int H>
__global__ __launch_bounds__(256) void gat_fused_kernel(const int* __restrict__ offs,
                                                        const int* __restrict__ csr,
                                                        const float* __restrict__ als,
                                                        const float* __restrict__ ald,
                                                        const u16* __restrict__ h,
                                                        u16* __restrict__ out, int N) {
    __shared__ float lalpha[8][32 * H];
    __shared__ int lsrc[8][32];
    int hw = threadIdx.x >> 5;          // half-wave in block (0..7)
    int lane = threadIdx.x & 31;        // lane within half-wave
    int w = (blockIdx.x * 256 + threadIdx.x) >> 5;
    if (w >= N) return;
    int s0 = offs[w], s1 = offs[w + 1];
    float adl[H], e0[H], m[H], den[H];
#pragma unroll
    for (int hh = 0; hh < H; hh++) { adl[hh] = ald[w * H + hh]; m[hh] = -1e30f; }
    int i0 = s0 + lane;
    bool have = (i0 < s1);
    int src0 = 0;
    if (have) {
        src0 = csr[i0];
        if (H == 4) {
            float4 av = ((const float4*)als)[src0];
            float tmp[4] = {av.x, av.y, av.z, av.w};
#pragma unroll
            for (int hh = 0; hh < 4; hh++) {
                float e = tmp[hh] + adl[hh];
                e = e > 0.f ? e : 0.2f * e;
                e0[hh] = e; m[hh] = e;
            }
        } else {
            float e = als[src0] + adl[0];
            e = e > 0.f ? e : 0.2f * e;
            e0[0] = e; m[0] = e;
        }
    }
    for (int i = i0 + 32; i < s1; i += 32) {  // rare: deg > 32
        int s = csr[i];
#pragma unroll
        for (int hh = 0; hh < H; hh++) {
            float e = als[s * H + hh] + adl[hh];
            e = e > 0.f ? e : 0.2f * e;
            m[hh] = fmaxf(m[hh], e);
        }
    }
#pragma unroll
    for (int hh = 0; hh < H; hh++)
        for (int o = 16; o; o >>= 1) m[hh] = fmaxf(m[hh], __shfl_xor(m[hh], o));
#pragma unroll
    for (int hh = 0; hh < H; hh++) den[hh] = have ? __expf(e0[hh] - m[hh]) : 0.f;
    for (int i = i0 + 32; i < s1; i += 32) {
        int s = csr[i];
#pragma unroll
        for (int hh = 0; hh < H; hh++) {
            float e = als[s * H + hh] + adl[hh];
            e = e > 0.f ? e : 0.2f * e;
            den[hh] += __expf(e - m[hh]);
        }
    }
#pragma unroll
    for (int hh = 0; hh < H; hh++)
        for (int o = 16; o; o >>= 1) den[hh] += __shfl_xor(den[hh], o);
    float rden[H];
#pragma unroll
    for (int hh = 0; hh < H; hh++) rden[hh] = 1.f / (den[hh] + 1e-16f);
    // park chunk-0 alpha/src in per-half-wave LDS (same-wave DS order)
    if (have) {
        lsrc[hw][lane] = src0;
#pragma unroll
        for (int hh = 0; hh < H; hh++)
            lalpha[hw][lane * H + hh] = __expf(e0[hh] - m[hh]) * rden[hh];
    }
    int deg = s1 - s0;
    int cend = min(deg, 32);
    int myh = (H == 4) ? (lane >> 3) : 0;   // head = (lane*8)/64
    const int4* h16 = (const int4*)h;       // 32 int4 per 256-col row
    const float* la = lalpha[hw];
    const int* ls = lsrc[hw];
    float acc[8];
#pragma unroll
    for (int k2 = 0; k2 < 8; k2++) acc[k2] = 0.f;
    int i = 0;
    for (; i + 4 <= cend; i += 4) {
        int sa = ls[i], sb = ls[i + 1], sc = ls[i + 2], sd = ls[i + 3];
        float aa = la[i * H + myh];
        float ab = la[(i + 1) * H + myh];
        float ac = la[(i + 2) * H + myh];
        float ad = la[(i + 3) * H + myh];
        int4 ha = h16[(size_t)sa * 32 + lane];
        int4 hb = h16[(size_t)sb * 32 + lane];
        int4 hc = h16[(size_t)sc * 32 + lane];
        int4 hd = h16[(size_t)sd * 32 + lane];
        fma8(acc, aa, ha);
        fma8(acc, ab, hb);
        fma8(acc, ac, hc);
        fma8(acc, ad, hd);
    }
    for (; i < cend; i++) {
        int s = ls[i];
        float a = la[i * H + myh];
        fma8(acc, a, h16[(size_t)s * 32 + lane]);
    }
    for (int j = s0 + 32; j < s1; j++) {  // rare deg>32 tail: recompute alpha
        int s = csr[j];
        float e = als[s * H + myh] + adl[myh];
        e = e > 0.f ? e : 0.2f * e;
        float a = __expf(e - m[myh]) * rden[myh];
        fma8(acc, a, h16[(size_t)s * 32 + lane]);
    }
    int4 o;
    o.x = (int)((unsigned)f2bf(acc[0]) | ((unsigned)f2bf(acc[1]) << 16));
    o.y = (int)((unsigned)f2bf(acc[2]) | ((unsigned)f2bf(acc[3]) << 16));
    o.z = (int)((unsigned)f2bf(acc[4]) | ((unsigned)f2bf(acc[5]) << 16));
    o.w = (int)((unsigned)f2bf(acc[6]) | ((unsigned)f2bf(acc[7]) << 16));
    ((int4*)out)[(size_t)w * 32 + lane] = o;
}

// ---------------- BatchNorm stats (bf16 input; register acc) ------------------
__global__ __launch_bounds__(256) void bn_stats(const u16* __restrict__ agg, int N,
                                                float* __restrict__ sum, float* __restrict__ sq) {
    int t = threadIdx.x;
    int rows = (N + gridDim.x - 1) / gridDim.x;
    int r0 = blockIdx.x * rows, r1 = min(r0 + rows, N);
    if (r0 >= r1) return;
    float s = 0.f, q = 0.f;
    for (int r = r0; r < r1; r++) {
        float v = bf2f(agg[(size_t)r * 256 + t]);
        s += v;
        q = fmaf(v, v, q);
    }
    atomicAdd(&sum[t], s);
    atomicAdd(&sq[t], q);
}

// layer 2: bn-apply + relu + fused global-mean-pool (batch sorted)
__global__ __launch_bounds__(256) void bn_apply_pool(const u16* __restrict__ agg,
                                                     const float* __restrict__ sum,
                                                     const float* __restrict__ sq,
                                                     const float* __restrict__ g,
                                                     const float* __restrict__ be,
                                                     const int* __restrict__ batch,
                                                     u16* __restrict__ out,
                                                     float* __restrict__ pools,
                                                     int* __restrict__ cnt, int N) {
    int t = threadIdx.x;
    float inv = 1.f / (float)N;
    float mm = sum[t] * inv;
    float vv = fmaxf(sq[t] * inv - mm * mm, 0.f);
    float sc = rsqrtf(vv + 1e-5f) * g[t];
    float sh = be[t] - mm * sc;
    int rows = (N + gridDim.x - 1) / gridDim.x;
    int r0 = blockIdx.x * rows, r1 = min(r0 + rows, N);
    if (r0 >= r1) return;
    float acc = 0.f;
    int cur = batch[r0], c0 = 0;
    for (int r = r0; r < r1; r++) {
        int b = batch[r];  // wave-uniform scalar load
        if (b != cur) {
            atomicAdd(&pools[cur * 256 + t], acc);
            if (t == 0) atomicAdd(&cnt[cur], c0);
            acc = 0.f; c0 = 0; cur = b;
        }
        float v = bf2f(agg[(size_t)r * 256 + t]);
        float y = fmaxf(fmaf(v, sc, sh), 0.f);
        out[(size_t)r * 256 + t] = f2bf(y);
        acc += y; c0++;
    }
    atomicAdd(&pools[cur * 256 + t], acc);
    if (t == 0) atomicAdd(&cnt[cur], c0);
}

// shared = relu(gf @ W_sh + b_sh) fused with heads; one block per graph
__global__ __launch_bounds__(256) void shared_head_kernel(const float* __restrict__ pools,
                                                          const int* __restrict__ cnt,
                                                          const float* __restrict__ Wsh,
                                                          const float* __restrict__ bsh,
                                                          const float* __restrict__ Wnode,
                                                          const float* __restrict__ Wcrit,
                                                          const float* __restrict__ bcrit,
                                                          const float* __restrict__ Wtype,
                                                          const float* __restrict__ btype,
                                                          const u16* __restrict__ xn,
                                                          const int* __restrict__ tgt,
                                                          float* __restrict__ gdot,
                                                          float* __restrict__ out_tail) {
    __shared__ float gf[256], red[256];
    int b = blockIdx.x, t = threadIdx.x;
    gf[t] = pools[b * 256 + t] / fmaxf((float)cnt[b], 1.f);
    __syncthreads();
    float acc = bsh[t];
    for (int k = 0; k < 256; k++) acc = fmaf(gf[k], Wsh[k * 256 + t], acc);
    float s = fmaxf(acc, 0.f);
    int tn = tgt[b];
    float xnt = bf2f(xn[(size_t)tn * 256 + t]);
    float pg = s * Wnode[256 + t];
    float pv = s * Wcrit[t];
    float pt0 = s * Wtype[t * 4 + 0] + xnt * Wtype[(256 + t) * 4 + 0];
    float pt1 = s * Wtype[t * 4 + 1] + xnt * Wtype[(256 + t) * 4 + 1];
    float pt2 = s * Wtype[t * 4 + 2] + xnt * Wtype[(256 + t) * 4 + 2];
    float pt3 = s * Wtype[t * 4 + 3] + xnt * Wtype[(256 + t) * 4 + 3];
    auto bred = [&](float v) -> float {
        __syncthreads();
        red[t] = v;
        __syncthreads();
        for (int o = 128; o; o >>= 1) {
            if (t < o) red[t] += red[t + o];
            __syncthreads();
        }
        return red[0];
    };
    float rg = bred(pg);
    float rv = bred(pv);
    float r0 = bred(pt0);
    float r1 = bred(pt1);
    float r2 = bred(pt2);
    float r3 = bred(pt3);
    if (t == 0) {
        gdot[b] = rg;
        out_tail[32 + b] = rv + bcrit[0];
        out_tail[b * 4 + 0] = r0 + btype[0];
        out_tail[b * 4 + 1] = r1 + btype[1];
        out_tail[b * 4 + 2] = r2 + btype[2];
        out_tail[b * 4 + 3] = r3 + btype[3];
    }
}

// node_scores: one wave per node (bf16 x_nodes)
__global__ __launch_bounds__(256) void node_scores_kernel(const u16* __restrict__ xn,
                                                          const float* __restrict__ Wnode, const float* __restrict__ bnode,
                                                          const int* __restrict__ batch, const float* __restrict__ gdot,
                                                          float* __restrict__ out, int N) {
    int w = (blockIdx.x * 256 + threadIdx.x) >> 6;
    int lane = threadIdx.x & 63;
    if (w >= N) return;
    ushort4 xv = ((const ushort4*)(xn + (size_t)w * 256))[lane];
    float4 wv = ((const float4*)Wnode)[lane];
    float p = bf2f(xv.x) * wv.x + bf2f(xv.y) * wv.y + bf2f(xv.z) * wv.z + bf2f(xv.w) * wv.w;
    for (int o = 32; o; o >>= 1) p += __shfl_xor(p, o);
    if (lane == 0) out[w] = p + gdot[batch[w]] + bnode[0];
}

extern "C" void kernel_launch(void* const* d_in, const int* in_sizes, int n_in,
                              void* d_out, int out_size, void* d_ws, size_t ws_size,
                              hipStream_t stream) {
    const float* x = (const float*)d_in[0];
    const int* ei = (const int*)d_in[1];
    const int* batch = (const int*)d_in[2];
    const int* tgt = (const int*)d_in[3];
    const float* W1 = (const float*)d_in[4];
    const float* a1s = (const float*)d_in[5];
    const float* a1d = (const float*)d_in[6];
    // b1 (d_in[7]) / b2 (d_in[11]): constant column shifts cancel exactly in BatchNorm
    const float* W2 = (const float*)d_in[8];
    const float* a2s = (const float*)d_in[9];
    const float* a2d = (const float*)d_in[10];
    const float* g1 = (const float*)d_in[12];
    const float* be1 = (const float*)d_in[13];
    const float* g2 = (const float*)d_in[14];
    const float* be2 = (const float*)d_in[15];
    const float* Wsh = (const float*)d_in[16];
    const float* bsh = (const float*)d_in[17];
    const float* Wnode = (const float*)d_in[18];
    const float* bnode = (const float*)d_in[19];
    const float* Wtype = (const float*)d_in[20];
    const float* btype = (const float*)d_in[21];
    const float* Wcrit = (const float*)d_in[22];
    const float* bcrit = (const float*)d_in[23];

    const int N = in_sizes[2];
    const int E = in_sizes[1] / 2;
    const int Et = E + N;
    const int nb = (N + 255) / 256;   // scan blocks

    // ---- workspace carve (~85 MB) ----
    char* w = (char*)d_ws;
    size_t off = 0;
    auto carve = [&](size_t bytes) -> char* {
        char* p = w + off;
        off = (off + bytes + 255) & ~(size_t)255;
        return p;
    };
    u16* agg_bf = (u16*)carve((size_t)N * 256 * 2);    // bf16 aggregation (both layers)
    u16* h_bf = (u16*)carve((size_t)N * 256 * 2);      // h1 -> h2 (gemm outputs)
    u16* y_bf = (u16*)carve((size_t)N * 256 * 2);      // x_nodes (bn2 out)
    u16* W1p = (u16*)carve(16 * 2 * 512 * 2);          // packed W1 frags
    u16* W2p = (u16*)carve(16 * 8 * 512 * 2);          // packed W2 frags
    float* al1s = (float*)carve((size_t)N * 4 * 4);
    float* al1d = (float*)carve((size_t)N * 4 * 4);
    float* al2s = (float*)carve((size_t)N * 4);
    float* al2d = (float*)carve((size_t)N * 4);
    int* offs = (int*)carve((size_t)(N + 1) * 4);
    int* cursor = (int*)carve((size_t)N * 4);
    int* csr = (int*)carve((size_t)Et * 4);
    int* excl = (int*)carve((size_t)N * 4);
    int* bsum = (int*)carve((size_t)nb * 4);
    int* bbase = (int*)carve((size_t)nb * 4);
    int* stotal = (int*)carve(64);
    float* gdot = (float*)carve(64);
    char* zero0 = w + off;
    int* counts = (int*)carve((size_t)N * 4);
    float* bn1s = (float*)carve(1024);
    float* bn1q = (float*)carve(1024);
    float* bn2s = (float*)carve(1024);
    float* bn2q = (float*)carve(1024);
    float* pools = (float*)carve(8 * 256 * 4);
    int* cnt = (int*)carve(64);
    size_t zbytes = (size_t)((w + off) - zero0);
    hipMemsetAsync(zero0, 0, zbytes, stream);

    int wavesPerGrid = (N + 3) / 4;                  // 4 node-waves per 256-thread block
    int halfGrid = (N + 7) / 8;                      // 8 node-half-waves per block
    int mfmaGrid = (((N + 31) / 32) + 3) / 4;        // 4 32-row tiles (waves) per block

    // ---- CSR build (3-phase parallel scan) + weight prep ----
    hist_kernel<<<(Et + 255) / 256, 256, 0, stream>>>(ei, E, N, counts);
    scan_p1<<<nb, 256, 0, stream>>>(counts, N, excl, bsum);
    scan_p2<<<1, 256, 0, stream>>>(bsum, nb, bbase, stotal);
    scan_p3<<<nb, 256, 0, stream>>>(excl, bbase, stotal, N, offs, cursor);
    scatter_kernel<<<(Et + 255) / 256, 256, 0, stream>>>(ei, E, N, cursor, csr);
    packW_both_kernel<<<(16 * 10 * 512 + 255) / 256, 256, 0, stream>>>(W1, W2, W1p, W2p);

    // ---- layer 1: GAT(4 heads); x converted to bf16 in gemm A-load ----
    gemm_mfma<64, 4, 0><<<mfmaGrid, 256, 0, stream>>>(x, W1p, h_bf, a1s, a1d, al1s, al1d,
                                                      bn1s, bn1q, g1, be1, N);
    gat_fused_kernel<4><<<halfGrid, 256, 0, stream>>>(offs, csr, al1s, al1d, h_bf, agg_bf, N);
    bn_stats<<<1024, 256, 0, stream>>>(agg_bf, N, bn1s, bn1q);

    // ---- layer 2: bn1-apply fused into gemm A-load; GAT(1) + BN2 + pool ----
    gemm_mfma<256, 1, 1><<<mfmaGrid, 256, 0, stream>>>(agg_bf, W2p, h_bf, a2s, a2d, al2s, al2d,
                                                       bn1s, bn1q, g1, be1, N);
    gat_fused_kernel<1><<<halfGrid, 256, 0, stream>>>(offs, csr, al2s, al2d, h_bf, agg_bf, N);
    bn_stats<<<1024, 256, 0, stream>>>(agg_bf, N, bn2s, bn2q);
    bn_apply_pool<<<1024, 256, 0, stream>>>(agg_bf, bn2s, bn2q, g2, be2, batch, y_bf, pools, cnt, N);

    // ---- heads ----
    shared_head_kernel<<<8, 256, 0, stream>>>(pools, cnt, Wsh, bsh, Wnode, Wcrit, bcrit,
                                              Wtype, btype, y_bf, tgt, gdot, (float*)d_out + N);
    node_scores_kernel<<<wavesPerGrid, 256, 0, stream>>>(y_bf, Wnode, bnode, batch, gdot,
                                                         (float*)d_out, N);
}